// Round 11
// baseline (3082.350 us; speedup 1.0000x reference)
//
#include <hip/hip_runtime.h>

#define NB 8
#define NN 1024
#define NC 32
#define NT 20
#define NTI 10
#define NM 32     // iteration block size (16 wanted + 16 guard)
#define NK 16     // K_SPACE
#define NMT 4     // M_TIME
#define WE 64     // ELL width (max entries per row)
#define NQ 128
#define GNN (NB*NN)
#define RSL 24    // edge slots held in registers in k_cheb
#define PTC 16    // tc per block in k_project
#define PSEG 16   // n-segments in k_project

__device__ __forceinline__ float gelu_f(float x){
  return 0.5f * x * (1.0f + erff(x * 0.70710678118654752f));
}
__device__ __forceinline__ unsigned wanghash(unsigned s){
  s = (s ^ 61u) ^ (s >> 16); s *= 9u; s ^= s >> 4; s *= 0x27d4eb2du; s ^= s >> 15;
  return s;
}

// ---------------- initial lift; also writes channel-major feat[b][c][n] ------
__global__ void k_build_h0(const float* __restrict__ x, const float* __restrict__ pos,
                           const float* __restrict__ Wp, const float* __restrict__ bp,
                           float* __restrict__ h, float* __restrict__ feat){
  int idx = blockIdx.x*256 + threadIdx.x;
  if (idx >= NB*NN*NT*NC) return;
  int c = idx & (NC-1);
  int t = (idx/NC) % NT;
  int n = (idx/(NC*NT)) & (NN-1);
  int b = idx/(NC*NT*NN);
  const float* xr = x + (b*NN + n)*NTI;
  float acc = bp[c];
  #pragma unroll
  for (int i=0;i<NTI;i++) acc += xr[i]*Wp[i*NC+c];
  acc += pos[(b*NN+n)*2+0]*Wp[10*NC+c];
  acc += pos[(b*NN+n)*2+1]*Wp[11*NC+c];
  float tv = (float)(10+t) * (1.0f/29.0f);
  acc += tv*Wp[12*NC+c];
  h[idx] = acc;
  if (t == 0) feat[(((size_t)b*NC + c)<<10) + n] = acc;
}

// ---------------- all-pairs distances, GEMM-style 64x64 tiles ----------------
// D[(b*NN+n)*NN + m] = sqrt(sum_c (feat[b][c][n]-feat[b][c][m])^2), c in order.
__global__ __launch_bounds__(256) void k_dist(const float* __restrict__ feat,
                          float* __restrict__ D){
  __shared__ float frow[NC][64];
  __shared__ float fcol[NC][64];
  int b = blockIdx.x & 7;
  int t = blockIdx.x >> 3;       // 0..255
  int r0 = (t >> 4) * 64;
  int m0 = (t & 15) * 64;
  const float* fb = feat + (((size_t)b*NC)<<10);
  #pragma unroll
  for (int it=0; it<8; it++){
    int idx = it*256 + threadIdx.x;
    int c = idx >> 6, j = idx & 63;
    frow[c][j] = fb[((size_t)c<<10) + r0 + j];
    fcol[c][j] = fb[((size_t)c<<10) + m0 + j];
  }
  __syncthreads();
  int rq = (threadIdx.x >> 4) << 2;
  int mq = (threadIdx.x & 15) << 2;
  float acc[4][4];
  #pragma unroll
  for (int i=0;i<4;i++)
    #pragma unroll
    for (int j=0;j<4;j++) acc[i][j] = 0.f;
  #pragma unroll 8
  for (int c=0;c<NC;c++){
    float rv[4], cv[4];
    #pragma unroll
    for (int i=0;i<4;i++) rv[i] = frow[c][rq+i];
    #pragma unroll
    for (int j=0;j<4;j++) cv[j] = fcol[c][mq+j];
    #pragma unroll
    for (int i=0;i<4;i++)
      #pragma unroll
      for (int j=0;j<4;j++){ float df = rv[i]-cv[j]; acc[i][j] += df*df; }
  }
  #pragma unroll
  for (int i=0;i<4;i++){
    float4 o;
    o.x = sqrtf(acc[i][0]); o.y = sqrtf(acc[i][1]);
    o.z = sqrtf(acc[i][2]); o.w = sqrtf(acc[i][3]);
    *(float4*)&D[(((size_t)(b<<10) + r0 + rq + i)<<10) + m0 + mq] = o;
  }
}

// ---------------- top-8 kNN + sigma from precomputed D -----------------------
// Per-lane visit order and FP accumulation order identical to fused version.
__global__ __launch_bounds__(256) void k_knn(const float* __restrict__ D,
                           float* __restrict__ knnd, int* __restrict__ knni,
                           double* __restrict__ sig, int* __restrict__ cnt){
  int wave = threadIdx.x >> 6;
  int lane = threadIdx.x & 63;
  int b  = blockIdx.x & 7;
  int rg = blockIdx.x >> 3;
  int row = (b<<10) + rg*4 + wave;
  const float* Dr = D + ((size_t)row << 10);
  float d8[8]; int i8[8];
  #pragma unroll
  for (int j=0;j<8;j++){ d8[j]=1e30f; i8[j]=0x3fffffff; }
  double ssum = 0.0;
  for (int tile=0; tile<8; tile++){
    int m = tile*128 + lane;
    float da = Dr[m];
    float db = Dr[m+64];
    ssum += (double)da;
    if (da < d8[7] || (da == d8[7] && m < i8[7])){
      d8[7] = da; i8[7] = m;
      #pragma unroll
      for (int j=6;j>=0;j--){
        bool sw = (d8[j+1] < d8[j]) || (d8[j+1]==d8[j] && i8[j+1]<i8[j]);
        if (sw){ float td=d8[j]; d8[j]=d8[j+1]; d8[j+1]=td;
                 int ti=i8[j]; i8[j]=i8[j+1]; i8[j+1]=ti; }
      }
    }
    int m2 = m + 64;
    ssum += (double)db;
    if (db < d8[7] || (db == d8[7] && m2 < i8[7])){
      d8[7] = db; i8[7] = m2;
      #pragma unroll
      for (int j=6;j>=0;j--){
        bool sw = (d8[j+1] < d8[j]) || (d8[j+1]==d8[j] && i8[j+1]<i8[j]);
        if (sw){ float td=d8[j]; d8[j]=d8[j+1]; d8[j+1]=td;
                 int ti=i8[j]; i8[j]=i8[j+1]; i8[j+1]=ti; }
      }
    }
  }
  #pragma unroll
  for (int off=32; off>0; off>>=1) ssum += __shfl_down(ssum, off);
  if (lane==0){ atomicAdd(&sig[b], ssum); cnt[row] = 8; }
  int ptr = 0;
  for (int sel=0; sel<8; sel++){
    float dv = 1e30f; int iv = 0x3fffffff;
    #pragma unroll
    for (int j=0;j<8;j++) if (j==ptr){ dv=d8[j]; iv=i8[j]; }
    float bd = dv; int bi = iv;
    #pragma unroll
    for (int off=32; off>0; off>>=1){
      float od = __shfl_xor(bd, off);
      int oi = __shfl_xor(bi, off);
      if (od < bd || (od == bd && oi < bi)){ bd = od; bi = oi; }
    }
    if (dv == bd && iv == bi) ptr++;
    if (lane == sel){ knnd[row*8+sel] = bd; knni[row*8+sel] = bi; }
  }
}

// ---------------- fused dist+knn fallback (R9 version, if ws too small) ------
__global__ __launch_bounds__(256) void k_dist_knn(const float* __restrict__ h,
                           const float* __restrict__ feat,
                           float* __restrict__ knnd, int* __restrict__ knni,
                           double* __restrict__ sig, int* __restrict__ cnt){
  __shared__ float fr_s[4][NC];
  int wave = threadIdx.x >> 6;
  int lane = threadIdx.x & 63;
  int b  = blockIdx.x & 7;
  int rg = blockIdx.x >> 3;
  int row = (b<<10) + rg*4 + wave;
  if (threadIdx.x < 4*NC){
    int w = threadIdx.x >> 5, c = threadIdx.x & 31;
    int rr = (b<<10) + rg*4 + w;
    fr_s[w][c] = h[((size_t)rr*NT)*NC + c];
  }
  __syncthreads();
  float d8[8]; int i8[8];
  #pragma unroll
  for (int j=0;j<8;j++){ d8[j]=1e30f; i8[j]=0x3fffffff; }
  double ssum = 0.0;
  const float* fc_b = feat + (((size_t)b*NC)<<10);
  for (int tile=0; tile<8; tile++){
    int m = tile*128 + lane;
    float d2a = 0.f, d2b = 0.f;
    #pragma unroll 8
    for (int c=0;c<NC;c++){
      float fc = fr_s[wave][c];
      const float* fp = fc_b + ((size_t)c<<10) + m;
      float dfa = fc - fp[0];
      float dfb = fc - fp[64];
      d2a += dfa*dfa; d2b += dfb*dfb;
    }
    float da = sqrtf(d2a);
    ssum += (double)da;
    if (da < d8[7] || (da == d8[7] && m < i8[7])){
      d8[7] = da; i8[7] = m;
      #pragma unroll
      for (int j=6;j>=0;j--){
        bool sw = (d8[j+1] < d8[j]) || (d8[j+1]==d8[j] && i8[j+1]<i8[j]);
        if (sw){ float td=d8[j]; d8[j]=d8[j+1]; d8[j+1]=td;
                 int ti=i8[j]; i8[j]=i8[j+1]; i8[j+1]=ti; }
      }
    }
    int m2 = m + 64;
    float db = sqrtf(d2b);
    ssum += (double)db;
    if (db < d8[7] || (db == d8[7] && m2 < i8[7])){
      d8[7] = db; i8[7] = m2;
      #pragma unroll
      for (int j=6;j>=0;j--){
        bool sw = (d8[j+1] < d8[j]) || (d8[j+1]==d8[j] && i8[j+1]<i8[j]);
        if (sw){ float td=d8[j]; d8[j]=d8[j+1]; d8[j+1]=td;
                 int ti=i8[j]; i8[j]=i8[j+1]; i8[j+1]=ti; }
      }
    }
  }
  #pragma unroll
  for (int off=32; off>0; off>>=1) ssum += __shfl_down(ssum, off);
  if (lane==0){ atomicAdd(&sig[b], ssum); cnt[row] = 8; }
  int ptr = 0;
  for (int sel=0; sel<8; sel++){
    float dv = 1e30f; int iv = 0x3fffffff;
    #pragma unroll
    for (int j=0;j<8;j++) if (j==ptr){ dv=d8[j]; iv=i8[j]; }
    float bd = dv; int bi = iv;
    #pragma unroll
    for (int off=32; off>0; off>>=1){
      float od = __shfl_xor(bd, off);
      int oi = __shfl_xor(bi, off);
      if (od < bd || (od == bd && oi < bi)){ bd = od; bi = oi; }
    }
    if (dv == bd && iv == bi) ptr++;
    if (lane == sel){ knnd[row*8+sel] = bd; knni[row*8+sel] = bi; }
  }
}

// ---------------- symmetrized sparse A in transposed ELL form ----------------
__global__ void k_build_ell(const float* __restrict__ knnd, const int* __restrict__ knni,
                            const double* __restrict__ sig, int* __restrict__ cnt,
                            unsigned short* __restrict__ ecolT, float* __restrict__ evalT){
  int row = blockIdx.x*256 + threadIdx.x;
  if (row >= NB*NN) return;
  int b = row >> 10;
  float sigma = (float)(sig[b] * (1.0/((double)NN*(double)NN)));
  float s2 = sigma*sigma;
  int rloc = row & (NN-1);
  #pragma unroll
  for (int j=0;j<8;j++){
    float d = knnd[row*8+j];
    int m = knni[row*8+j];
    float v = 0.5f * expf(-d/s2);
    ecolT[(size_t)j*GNN + row] = (unsigned short)m;
    evalT[(size_t)j*GNN + row] = v;
    int grow = (b<<10) + m;
    int p = atomicAdd(&cnt[grow], 1);
    if (p < WE){ ecolT[(size_t)p*GNN + grow] = (unsigned short)rloc;
                 evalT[(size_t)p*GNN + grow] = v; }
  }
}

__global__ void k_degnorm(const int* __restrict__ cnt, const float* __restrict__ evalT,
                          float* __restrict__ deg, float* __restrict__ dinv){
  int row = blockIdx.x*256 + threadIdx.x;
  if (row >= NB*NN) return;
  int c = cnt[row]; if (c > WE) c = WE;
  float s = 0.f;
  for (int j=0;j<c;j++) s += evalT[(size_t)j*GNN + row];
  deg[row] = s;
  dinv[row] = 1.0f/sqrtf(s + 1e-6f);
}

__global__ void k_normell(const int* __restrict__ cnt, const unsigned short* __restrict__ ecolT,
                          float* __restrict__ evalT, const float* __restrict__ deg,
                          const float* __restrict__ dinv, float* __restrict__ dval){
  int row = blockIdx.x*256 + threadIdx.x;
  if (row >= NB*NN) return;
  int b = row >> 10;
  const float* dv = dinv + (b<<10);
  float di = dinv[row];
  int c = cnt[row]; if (c > WE) c = WE;
  for (int j=0;j<c;j++){
    int col = ecolT[(size_t)j*GNN + row];
    evalT[(size_t)j*GNN + row] = evalT[(size_t)j*GNN + row] * (di * dv[col]);
  }
  dval[row] = di*di*deg[row];
}

// ---------------- eigensolver: init block -----------------------------------
__global__ void k_initX(const float* __restrict__ deg, float* __restrict__ X, float* __restrict__ aint){
  int idx = blockIdx.x*256+threadIdx.x;
  if (idx >= NB*NM*NN) return;
  int n = idx & (NN-1);
  int j = (idx >> 10) & (NM-1);
  int b = idx >> 15;
  float v;
  if (j == 0) v = sqrtf(deg[(b<<10)+n] + 1e-6f);   // exact 0-eigenvector of Lhat
  else {
    unsigned hsh = wanghash((unsigned)idx * 2654435761u + 12345u);
    v = ((hsh >> 8) * (1.0f/16777216.0f)) - 0.5f;
  }
  X[idx] = v;
  if (n == 0 && j == 1) aint[b] = 1.0f;
}

// ---------------- Chebyshev filter, one column per block, edges in regs ------
__global__ __launch_bounds__(512) void k_cheb(const int* __restrict__ cnt,
                        const unsigned short* __restrict__ ecolT,
                        const float* __restrict__ evalT, const float* __restrict__ dval,
                        float* __restrict__ X, const float* __restrict__ aint, int ndeg){
  __shared__ float bufA[NN];
  __shared__ float bufB[NN];
  int b = blockIdx.x & 7;
  int col = blockIdx.x >> 3;
  float a = aint[b];
  const float bhi = 2.0005f;
  float e  = 0.5f*(bhi - a);
  float cc = 0.5f*(bhi + a);
  float inv_e = 1.0f/e;
  const int rowbase = b << 10;
  float* Xc = X + ((size_t)b*NM + col)*NN;
  for (int n=threadIdx.x; n<NN; n+=512) bufA[n] = Xc[n];
  int r0 = threadIdx.x, r1 = threadIdx.x + 512;
  int c0 = cnt[rowbase+r0]; if (c0 > WE) c0 = WE;
  int c1 = cnt[rowbase+r1]; if (c1 > WE) c1 = WE;
  float dv0 = dval[rowbase+r0];
  float dv1 = dval[rowbase+r1];
  float ev0[RSL], ev1[RSL];
  int   ic0[RSL], ic1[RSL];
  #pragma unroll
  for (int j=0;j<RSL;j++){
    ic0[j] = (j<c0)? (int)ecolT[(size_t)j*GNN + rowbase + r0] : 0;
    ev0[j] = (j<c0)? evalT[(size_t)j*GNN + rowbase + r0] : 0.f;
    ic1[j] = (j<c1)? (int)ecolT[(size_t)j*GNN + rowbase + r1] : 0;
    ev1[j] = (j<c1)? evalT[(size_t)j*GNN + rowbase + r1] : 0.f;
  }
  int e0 = c0 - RSL; if (e0 < 0) e0 = 0;
  int e1 = c1 - RSL; if (e1 < 0) e1 = 0;
  int emax = (e0 > e1)? e0 : e1;
  const unsigned short* pe0 = ecolT + (size_t)RSL*GNN + rowbase + r0;
  const unsigned short* pe1 = ecolT + (size_t)RSL*GNN + rowbase + r1;
  const float* pv0 = evalT + (size_t)RSL*GNN + rowbase + r0;
  const float* pv1 = evalT + (size_t)RSL*GNN + rowbase + r1;
  __syncthreads();
  float* cur = bufA; float* prv = bufB;
  for (int k=0;k<ndeg;k++){
    float f = (k==0)? inv_e : 2.0f*inv_e;
    float x0 = cur[r0], x1 = cur[r1];
    float acc0 = dv0*x0, acc1 = dv1*x1;
    #pragma unroll
    for (int j=0;j<RSL;j++){
      acc0 -= ev0[j]*cur[ic0[j]];
      acc1 -= ev1[j]*cur[ic1[j]];
    }
    for (int j=0;j<emax;j++){   // rare overflow rows
      if (j < e0) acc0 -= pv0[(size_t)j*GNN] * cur[pe0[(size_t)j*GNN]];
      if (j < e1) acc1 -= pv1[(size_t)j*GNN] * cur[pe1[(size_t)j*GNN]];
    }
    float n0 = f*(acc0 - cc*x0);
    float n1 = f*(acc1 - cc*x1);
    if (k > 0){ n0 -= prv[r0]; n1 -= prv[r1]; }
    prv[r0] = n0; prv[r1] = n1;
    float* t_ = cur; cur = prv; prv = t_;
    __syncthreads();
  }
  for (int n=threadIdx.x; n<NN; n+=512) Xc[n] = cur[n];
}

// ---------------- G = A^T B (f64 accumulate), one row of G per wg ------------
__global__ void k_gram(const float* __restrict__ A, const float* __restrict__ Bm,
                       double* __restrict__ G){
  __shared__ float ai[NN];
  __shared__ double pd[NM][8];
  int b = blockIdx.x & 7, i = blockIdx.x >> 3;
  const float* Ac = A + ((size_t)b*NM + i)*NN;
  for (int n=threadIdx.x; n<NN; n+=256) ai[n] = Ac[n];
  __syncthreads();
  int j = threadIdx.x & 31, seg = threadIdx.x >> 5;
  const float* Bc = Bm + ((size_t)b*NM + j)*NN + seg*128;
  const float* as = ai + seg*128;
  double s = 0.0;
  for (int n=0;n<128;n++) s += (double)as[n]*(double)Bc[n];
  pd[j][seg] = s;
  __syncthreads();
  if (threadIdx.x < NM){
    double t = 0.0;
    #pragma unroll
    for (int q=0;q<8;q++) t += pd[threadIdx.x][q];
    G[((size_t)b*NM + i)*NM + threadIdx.x] = t;
  }
}

// ---------------- chol(G)->R^{-1}->apply, 1-wave blocks, 64 nodes/block ------
__global__ __launch_bounds__(64) void k_cholapply(const double* __restrict__ G,
                        const float* __restrict__ Xin, float* __restrict__ Xout,
                        float* __restrict__ aint, int reset){
  __shared__ double L[NM][NM];
  __shared__ double Ri[NM][NM];
  int b = blockIdx.x >> 4;
  int seg = blockIdx.x & 15;
  int tid = threadIdx.x;
  for (int idx=tid; idx<NM*NM; idx+=64) L[idx>>5][idx&31] = G[(size_t)b*NM*NM + idx];
  __syncthreads();
  for (int k=0;k<NM;k++){
    if (tid == 0){
      double orig = L[k][k];
      double s = orig;
      for (int p=0;p<k;p++) s -= L[k][p]*L[k][p];
      double floorv = orig*1e-15; if (floorv < 1e-30) floorv = 1e-30;
      if (s < floorv) s = floorv;
      L[k][k] = sqrt(s);
    }
    __syncthreads();
    if (tid > k && tid < NM){
      double s = L[tid][k];
      for (int p=0;p<k;p++) s -= L[tid][p]*L[k][p];
      L[tid][k] = s / L[k][k];
    }
    __syncthreads();
  }
  if (tid < NM){
    int j = tid;
    Ri[j][j] = 1.0 / L[j][j];
    for (int i=j-1;i>=0;i--){
      double s = 0.0;
      for (int k2=i+1;k2<=j;k2++) s += L[k2][i]*Ri[k2][j];
      Ri[i][j] = -s / L[i][i];
    }
  }
  __syncthreads();
  int n = seg*64 + tid;
  float xv[NM];
  #pragma unroll
  for (int j=0;j<NM;j++) xv[j] = Xin[((size_t)b*NM + j)*NN + n];
  for (int jn=0;jn<NM;jn++){
    double acc = 0.0;
    for (int j=0;j<=jn;j++) acc += (double)xv[j] * Ri[j][jn];
    Xout[((size_t)b*NM + jn)*NN + n] = (float)acc;
  }
  if (reset && seg==0 && tid==0) aint[b] = 0.02f;
}

// ---------------- fused spmv + Gram row + Gershgorin interval bound ----------
__global__ __launch_bounds__(256) void k_spmv_gersh(const int* __restrict__ cnt,
                        const unsigned short* __restrict__ ecolT,
                        const float* __restrict__ evalT, const float* __restrict__ dval,
                        const float* __restrict__ X, float* __restrict__ aint){
  __shared__ float xc[NN];
  __shared__ float yc[NN];
  __shared__ double pd[NM][8];
  int b = blockIdx.x & 7, j = blockIdx.x >> 3;
  const float* Xc = X + ((size_t)b*NM + j)*NN;
  for (int n=threadIdx.x; n<NN; n+=256) xc[n] = Xc[n];
  __syncthreads();
  int rowbase = b << 10;
  for (int r=threadIdx.x; r<NN; r+=256){
    int c = cnt[rowbase+r]; if (c > WE) c = WE;
    float acc = dval[rowbase+r]*xc[r];
    const unsigned short* pe = ecolT + rowbase + r;
    const float* pv = evalT + rowbase + r;
    for (int jj=0;jj<c;jj++){
      acc -= pv[0]*xc[pe[0]];
      pe += GNN; pv += GNN;
    }
    yc[r] = acc;
  }
  __syncthreads();
  int i = threadIdx.x >> 3, seg = threadIdx.x & 7;
  const float* Xi = X + ((size_t)b*NM + i)*NN + seg*128;
  const float* ys = yc + seg*128;
  double s = 0.0;
  for (int k=0;k<128;k++) s += (double)Xi[k]*(double)ys[k];
  pd[i][seg] = s;
  __syncthreads();
  if (threadIdx.x < NM){
    double g = 0.0;
    #pragma unroll
    for (int q=0;q<8;q++) g += pd[threadIdx.x][q];
    double contrib = (threadIdx.x==j)? g : fabs(g);
    #pragma unroll
    for (int off=16; off>0; off>>=1) contrib += __shfl_down(contrib, off, 32);
    if (threadIdx.x == 0){
      float av = (float)contrib*1.02f + 1e-4f;
      av = fminf(fmaxf(av, 0.02f), 1.5f);
      atomicMax((unsigned int*)&aint[b], __float_as_uint(av));
    }
  }
}

// ---------------- fused spmv + Gram row write (final RR) ---------------------
__global__ __launch_bounds__(256) void k_spmv_gram(const int* __restrict__ cnt,
                        const unsigned short* __restrict__ ecolT,
                        const float* __restrict__ evalT, const float* __restrict__ dval,
                        const float* __restrict__ X, double* __restrict__ G){
  __shared__ float xc[NN];
  __shared__ float yc[NN];
  __shared__ double pd[NM][8];
  int b = blockIdx.x & 7, j = blockIdx.x >> 3;
  const float* Xc = X + ((size_t)b*NM + j)*NN;
  for (int n=threadIdx.x; n<NN; n+=256) xc[n] = Xc[n];
  __syncthreads();
  int rowbase = b << 10;
  for (int r=threadIdx.x; r<NN; r+=256){
    int c = cnt[rowbase+r]; if (c > WE) c = WE;
    float acc = dval[rowbase+r]*xc[r];
    const unsigned short* pe = ecolT + rowbase + r;
    const float* pv = evalT + rowbase + r;
    for (int jj=0;jj<c;jj++){
      acc -= pv[0]*xc[pe[0]];
      pe += GNN; pv += GNN;
    }
    yc[r] = acc;
  }
  __syncthreads();
  int i = threadIdx.x >> 3, seg = threadIdx.x & 7;
  const float* Xi = X + ((size_t)b*NM + i)*NN + seg*128;
  const float* ys = yc + seg*128;
  double s = 0.0;
  for (int k=0;k<128;k++) s += (double)Xi[k]*(double)ys[k];
  pd[i][seg] = s;
  __syncthreads();
  if (threadIdx.x < NM){
    double g = 0.0;
    #pragma unroll
    for (int q=0;q<8;q++) g += pd[threadIdx.x][q];
    G[((size_t)b*NM + j)*NM + threadIdx.x] = g;   // G[j][i]; jacobi symmetrizes
  }
}

// ---------------- 32x32 Jacobi (1-wave block), Vp out (f32) ------------------
__global__ __launch_bounds__(64) void k_jacobi(const double* __restrict__ Gd,
                        float* __restrict__ Vpf, int sweeps){
  __shared__ float S[NM][NM];
  __shared__ float V[NM][NM];
  __shared__ float cs_[16], sn_[16];
  __shared__ int pp_[16], qq_[16];
  __shared__ int perm[NM];
  int b = blockIdx.x, l = threadIdx.x;
  for (int idx=l; idx<NM*NM; idx+=64){
    int i = idx>>5, j = idx&31;
    S[i][j] = (float)(0.5*(Gd[(size_t)b*NM*NM + i*NM + j] + Gd[(size_t)b*NM*NM + j*NM + i]));
    V[i][j] = (i==j)? 1.0f : 0.0f;
  }
  __syncthreads();
  for (int sw=0; sw<sweeps; sw++){
    for (int r=0; r<31; r++){
      if (l < 16){
        int p, q;
        if (l == 0){ p = r; q = 31; }
        else { p = (r + l) % 31; q = (r + 31 - l) % 31; }
        if (p > q){ int t_=p; p=q; q=t_; }
        float apq = S[p][q];
        float c = 1.0f, s = 0.0f;
        if (fabsf(apq) > 1e-30f){
          float tau = (S[q][q] - S[p][p]) / (2.0f*apq);
          float tt = (tau >= 0.f ? 1.0f : -1.0f) / (fabsf(tau) + sqrtf(1.0f + tau*tau));
          c = 1.0f/sqrtf(1.0f + tt*tt); s = tt*c;
        }
        cs_[l]=c; sn_[l]=s; pp_[l]=p; qq_[l]=q;
      }
      __syncthreads();
      for (int tsk=l; tsk<512; tsk+=64){
        int i = tsk >> 4, kk = tsk & 15;
        int p = pp_[kk], q = qq_[kk];
        float c = cs_[kk], s = sn_[kk];
        float sp = S[i][p], sq = S[i][q];
        S[i][p] = c*sp - s*sq; S[i][q] = s*sp + c*sq;
        float vp = V[i][p], vq = V[i][q];
        V[i][p] = c*vp - s*vq; V[i][q] = s*vp + c*vq;
      }
      __syncthreads();
      for (int tsk=l; tsk<512; tsk+=64){
        int jc = tsk >> 4, kk = tsk & 15;
        int p = pp_[kk], q = qq_[kk];
        float c = cs_[kk], s = sn_[kk];
        float sp = S[p][jc], sq = S[q][jc];
        S[p][jc] = c*sp - s*sq; S[q][jc] = s*sp + c*sq;
      }
      __syncthreads();
    }
  }
  // parallel rank sort of diag(S) ascending (tie-break by index)
  if (l < NM){
    float v = S[l][l];
    int rank = 0;
    #pragma unroll
    for (int i=0;i<NM;i++){
      float vi = S[i][i];
      rank += (vi < v || (vi == v && i < l)) ? 1 : 0;
    }
    perm[rank] = l;
  }
  __syncthreads();
  for (int idx=l; idx<NM*NM; idx+=64){
    int i = idx>>5, j = idx&31;
    Vpf[(size_t)b*NM*NM + i*NM + j] = V[i][perm[j]];
  }
}

// ---------------- Xout = Xin * Vp (f32), quarter of nodes per block ----------
__global__ __launch_bounds__(256) void k_applyVf(const float* __restrict__ Xin,
                        const float* __restrict__ Vpf, float* __restrict__ Xout){
  __shared__ float Ms[NM*NM];
  int b = blockIdx.x >> 2;
  int n = (blockIdx.x & 3)*256 + threadIdx.x;
  for (int idx=threadIdx.x; idx<NM*NM; idx+=256) Ms[idx] = Vpf[(size_t)b*NM*NM + idx];
  __syncthreads();
  float xv[NM];
  #pragma unroll
  for (int j=0;j<NM;j++) xv[j] = Xin[((size_t)b*NM + j)*NN + n];
  #pragma unroll
  for (int jn=0;jn<NM;jn++){
    float acc = 0.f;
    #pragma unroll
    for (int j=0;j<NM;j++) acc += xv[j]*Ms[j*NM + jn];
    Xout[((size_t)b*NM + jn)*NN + n] = acc;
  }
}

// ---------------- xs[b][k][tc] = sum_n X[b][k][n] * h[b][n][tc] --------------
__global__ __launch_bounds__(256) void k_project(const float* __restrict__ X, const float* __restrict__ h,
                          float* __restrict__ xs){
  __shared__ float Xs[NK][NN];             // 64KB
  __shared__ float red[PSEG][NK][PTC+1];   // ~17KB
  int b = blockIdx.x & 7;
  int chunk = blockIdx.x >> 3;             // 0..39
  int tc0 = chunk * PTC;
  for (int idx=threadIdx.x; idx<NK*NN; idx+=256){
    int k = idx >> 10, n = idx & (NN-1);
    Xs[k][n] = X[((size_t)b*NM + k)*NN + n];
  }
  __syncthreads();
  int tcl = threadIdx.x & (PTC-1);
  int seg = threadIdx.x >> 4;              // 0..15
  const float* hb = h + (size_t)b*NN*NT*NC + tc0 + tcl;
  float acc[NK];
  #pragma unroll
  for (int k=0;k<NK;k++) acc[k]=0.f;
  int n0 = seg*(NN/PSEG);
  for (int n=n0; n<n0+(NN/PSEG); n++){
    float v = hb[(size_t)n*NT*NC];
    #pragma unroll
    for (int k=0;k<NK;k++) acc[k] += Xs[k][n]*v;
  }
  #pragma unroll
  for (int k=0;k<NK;k++) red[seg][k][tcl] = acc[k];
  __syncthreads();
  int k = threadIdx.x >> 4;
  int t2 = threadIdx.x & (PTC-1);
  float s = 0.f;
  #pragma unroll
  for (int q=0;q<PSEG;q++) s += red[q][k][t2];
  xs[((size_t)b*NK + k)*NT*NC + tc0 + t2] = s;
}

// ---------------- rfft(:4) -> complex channel mix -> irfft -------------------
__global__ __launch_bounds__(64) void k_timefilter(const float* __restrict__ xs, const float* __restrict__ fwr,
                             const float* __restrict__ fwi, float* __restrict__ osb, int layer){
  __shared__ float xst[NT*NC];
  __shared__ float xfr[NC][NMT];
  __shared__ float xfi[NC][NMT];
  int b = blockIdx.x >> 4, k = blockIdx.x & 15;
  const float* xin = xs + ((size_t)b*NK + k)*NT*NC;
  for (int idx=threadIdx.x; idx<NT*NC; idx+=64) xst[idx] = xin[idx];
  __syncthreads();
  int l = threadIdx.x;
  if (l < NC){
    float ar0=0,ar1=0,ar2=0,ar3=0, ai1=0,ai2=0,ai3=0;
    for (int t=0;t<NT;t++){
      float v = xst[t*NC + l];
      float w1 = 0.31415926535897932f * (float)t;  // 2*pi*t/20
      ar0 += v;
      ar1 += v*cosf(w1);       ai1 -= v*sinf(w1);
      ar2 += v*cosf(2.f*w1);   ai2 -= v*sinf(2.f*w1);
      ar3 += v*cosf(3.f*w1);   ai3 -= v*sinf(3.f*w1);
    }
    xfr[l][0]=ar0; xfi[l][0]=0.f;
    xfr[l][1]=ar1; xfi[l][1]=ai1;
    xfr[l][2]=ar2; xfi[l][2]=ai2;
    xfr[l][3]=ar3; xfi[l][3]=ai3;
  }
  __syncthreads();
  if (l < NC){
    int o = l;
    float ofr[NMT], ofi[NMT];
    #pragma unroll
    for (int f=0; f<NMT; f++){ ofr[f]=0.f; ofi[f]=0.f; }
    for (int i=0;i<NC;i++){
      size_t wbase = ((((size_t)layer*NC + i)*NC + o)*NK + k)*NMT;
      #pragma unroll
      for (int f=0; f<NMT; f++){
        float wr = fwr[wbase+f], wi2 = fwi[wbase+f];
        float xr = xfr[i][f], xi = xfi[i][f];
        ofr[f] += xr*wr - xi*wi2;
        ofi[f] += xr*wi2 + xi*wr;
      }
    }
    float* outp = osb + ((size_t)b*NK + k)*NT*NC;
    for (int t=0;t<NT;t++){
      float w1 = 0.31415926535897932f * (float)t;
      float acc = ofr[0];
      acc += 2.f*(ofr[1]*cosf(w1)     - ofi[1]*sinf(w1));
      acc += 2.f*(ofr[2]*cosf(2.f*w1) - ofi[2]*sinf(2.f*w1));
      acc += 2.f*(ofr[3]*cosf(3.f*w1) - ofi[3]*sinf(3.f*w1));
      outp[t*NC + o] = acc * 0.05f;
    }
  }
}

// ---------------- h' = basis*os + cw*h + cb, gelu; also writes feat ----------
__global__ __launch_bounds__(256) void k_update(const float* __restrict__ X, const float* __restrict__ osb,
                         const float* __restrict__ h, const float* __restrict__ cw,
                         const float* __restrict__ cb, float* __restrict__ hout,
                         float* __restrict__ feat, int layer){
  __shared__ float os_s[NK*NT*NC];   // 40KB
  __shared__ float cwT[NC*NC];
  __shared__ float Xl[NK][32];
  __shared__ float cbs[NC];
  int b = blockIdx.x & 7;
  int n0 = (blockIdx.x >> 3)*32;
  for (int idx=threadIdx.x; idx<NK*NT*NC; idx+=256) os_s[idx] = osb[(size_t)b*NK*NT*NC + idx];
  for (int idx=threadIdx.x; idx<NC*NC; idx+=256){
    int o = idx/NC, i = idx%NC;
    cwT[i*NC + o] = cw[((size_t)layer*NC + o)*NC + i];
  }
  if (threadIdx.x < NC) cbs[threadIdx.x] = cb[layer*NC + threadIdx.x];
  for (int idx=threadIdx.x; idx<NK*32; idx+=256){
    int k = idx >> 5, nl = idx & 31;
    Xl[k][nl] = X[((size_t)b*NM + k)*NN + n0 + nl];
  }
  __syncthreads();
  for (int tsk=threadIdx.x; tsk<32*NT; tsk+=256){
    int t = tsk % NT, nl = tsk / NT;
    int n = n0 + nl;
    const float* hr = h + (((size_t)b*NN + n)*NT + t)*NC;
    float acc[NC];
    #pragma unroll
    for (int o=0;o<NC;o++) acc[o] = cbs[o];
    #pragma unroll
    for (int k=0;k<NK;k++){
      float xv = Xl[k][nl];
      const float* osr = os_s + (k*NT + t)*NC;
      #pragma unroll
      for (int o=0;o<NC;o++) acc[o] += xv*osr[o];
    }
    for (int i=0;i<NC;i++){
      float hv = hr[i];
      const float* cwr = cwT + i*NC;
      #pragma unroll
      for (int o=0;o<NC;o++) acc[o] += hv*cwr[o];
    }
    float* outp = hout + (((size_t)b*NN + n)*NT + t)*NC;
    if (layer < 3){
      #pragma unroll
      for (int o=0;o<NC;o++){
        float v = gelu_f(acc[o]);
        outp[o] = v;
        if (t == 0) feat[(((size_t)b*NC + o)<<10) + n] = v;
      }
    } else {
      #pragma unroll
      for (int o=0;o<NC;o++){
        outp[o] = acc[o];
        if (t == 0) feat[(((size_t)b*NC + o)<<10) + n] = acc[o];
      }
    }
  }
}

// ---------------- head: gelu(h@q1w+q1b)@q2w + q2b ----------------------------
__global__ __launch_bounds__(256) void k_head(const float* __restrict__ h, const float* __restrict__ q1w,
                       const float* __restrict__ q1b, const float* __restrict__ q2w,
                       const float* __restrict__ q2b, float* __restrict__ out){
  __shared__ float w1[NC*NQ];
  __shared__ float b1[NQ], w2[NQ];
  for (int idx=threadIdx.x; idx<NC*NQ; idx+=256) w1[idx] = q1w[idx];
  if (threadIdx.x < NQ){ b1[threadIdx.x] = q1b[threadIdx.x]; w2[threadIdx.x] = q2w[threadIdx.x]; }
  __syncthreads();
  int idx = blockIdx.x*256 + threadIdx.x;
  if (idx >= NB*NN*NT) return;
  const float* hr = h + (size_t)idx*NC;
  float hv[NC];
  #pragma unroll
  for (int i=0;i<NC;i++) hv[i] = hr[i];
  float res = q2b[0];
  for (int j=0;j<NQ;j++){
    float z = b1[j];
    #pragma unroll
    for (int i=0;i<NC;i++) z += hv[i]*w1[i*NQ + j];
    res += gelu_f(z)*w2[j];
  }
  out[idx] = res;
}

// ============================================================================
extern "C" void kernel_launch(void* const* d_in, const int* in_sizes, int n_in,
                              void* d_out, int out_size, void* d_ws, size_t ws_size,
                              hipStream_t stream){
  (void)in_sizes; (void)n_in; (void)out_size;
  const float* x   = (const float*)d_in[0];
  const float* pos = (const float*)d_in[1];
  const float* Wp  = (const float*)d_in[2];
  const float* bp  = (const float*)d_in[3];
  const float* fwr = (const float*)d_in[4];
  const float* fwi = (const float*)d_in[5];
  const float* cw  = (const float*)d_in[6];
  const float* cb  = (const float*)d_in[7];
  const float* q1w = (const float*)d_in[8];
  const float* q1b = (const float*)d_in[9];
  const float* q2w = (const float*)d_in[10];
  const float* q2b = (const float*)d_in[11];

  char* p = (char*)d_ws;
  auto take = [&](size_t bytes)->void*{
    void* r = (void*)p;
    p += (bytes + 255) & ~(size_t)255;
    return r;
  };
  float*  hA    = (float*) take(sizeof(float)*NB*NN*NT*NC);
  float*  hB    = (float*) take(sizeof(float)*NB*NN*NT*NC);
  float*  featb = (float*) take(sizeof(float)*NB*NC*NN);
  float*  knnd  = (float*) take(sizeof(float)*NB*NN*8);
  int*    knni  = (int*)   take(sizeof(int)*NB*NN*8);
  double* sig   = (double*)take(sizeof(double)*NB);
  int*    cntb  = (int*)   take(sizeof(int)*NB*NN);
  unsigned short* ecolT = (unsigned short*) take(sizeof(unsigned short)*(size_t)GNN*WE);
  float*  evalT = (float*) take(sizeof(float)*(size_t)GNN*WE);
  float*  deg   = (float*) take(sizeof(float)*NB*NN);
  float*  dinv  = (float*) take(sizeof(float)*NB*NN);
  float*  dval  = (float*) take(sizeof(float)*NB*NN);
  float*  Xb    = (float*) take(sizeof(float)*NB*NM*NN);
  float*  Yb    = (float*) take(sizeof(float)*NB*NM*NN);
  double* Gd    = (double*)take(sizeof(double)*NB*NM*NM);
  float*  Vpf   = (float*) take(sizeof(float)*NB*NM*NM);
  float*  aint  = (float*) take(sizeof(float)*NB);
  float*  xs    = (float*) take(sizeof(float)*NB*NK*NT*NC);
  float*  osb   = (float*) take(sizeof(float)*NB*NK*NT*NC);
  if ((size_t)(p - (char*)d_ws) > ws_size) return;  // ws too small -> loud failure
  // optional 32MB distance matrix (split path); fall back to fused if no room
  float* Dbuf = nullptr;
  {
    size_t used = (size_t)(p - (char*)d_ws);
    size_t needD = ((sizeof(float)*(size_t)GNN*NN) + 255) & ~(size_t)255;
    if (used + needD <= ws_size) Dbuf = (float*)take(sizeof(float)*(size_t)GNN*NN);
  }

  k_build_h0<<<(NB*NN*NT*NC+255)/256, 256, 0, stream>>>(x, pos, Wp, bp, hA, featb);

  float* hcur = hA; float* hnext = hB;
  for (int layer=0; layer<4; layer++){
    hipMemsetAsync(sig, 0, sizeof(double)*NB, stream);
    if (Dbuf){
      k_dist<<<NB*256, 256, 0, stream>>>(featb, Dbuf);
      k_knn<<<NB*NN/4, 256, 0, stream>>>(Dbuf, knnd, knni, sig, cntb);
    } else {
      k_dist_knn<<<NB*NN/4, 256, 0, stream>>>(hcur, featb, knnd, knni, sig, cntb);
    }
    k_build_ell<<<NB*NN/256, 256, 0, stream>>>(knnd, knni, sig, cntb, ecolT, evalT);
    k_degnorm<<<NB*NN/256, 256, 0, stream>>>(cntb, evalT, deg, dinv);
    k_normell<<<NB*NN/256, 256, 0, stream>>>(cntb, ecolT, evalT, deg, dinv, dval);
    k_initX<<<NB*NM*NN/256, 256, 0, stream>>>(deg, Xb, aint);
    float* cur = Xb; float* oth = Yb;
    // round 0: deg 24 on [1.0, 2.0005], then QR + interval estimate
    k_cheb<<<NB*NM, 512, 0, stream>>>(cntb, ecolT, evalT, dval, cur, aint, 24);
    k_gram<<<NB*NM, 256, 0, stream>>>(cur, cur, Gd);
    k_cholapply<<<NB*16, 64, 0, stream>>>(Gd, cur, oth, aint, 1);
    { float* t_ = cur; cur = oth; oth = t_; }
    k_spmv_gersh<<<NB*NM, 256, 0, stream>>>(cntb, ecolT, evalT, dval, cur, aint);
    // round 1: deg 32 on adapted interval, then QR
    k_cheb<<<NB*NM, 512, 0, stream>>>(cntb, ecolT, evalT, dval, cur, aint, 32);
    k_gram<<<NB*NM, 256, 0, stream>>>(cur, cur, Gd);
    k_cholapply<<<NB*16, 64, 0, stream>>>(Gd, cur, oth, aint, 0);
    { float* t_ = cur; cur = oth; oth = t_; }
    // final Rayleigh-Ritz: G = X^T L X (fused), Jacobi (1 sweep), apply
    k_spmv_gram<<<NB*NM, 256, 0, stream>>>(cntb, ecolT, evalT, dval, cur, Gd);
    k_jacobi<<<NB, 64, 0, stream>>>(Gd, Vpf, 1);
    k_applyVf<<<NB*4, 256, 0, stream>>>(cur, Vpf, oth);
    { float* t_ = cur; cur = oth; oth = t_; }

    k_project<<<NB*40, 256, 0, stream>>>(cur, hcur, xs);
    k_timefilter<<<NB*NK, 64, 0, stream>>>(xs, fwr, fwi, osb, layer);
    k_update<<<NB*32, 256, 0, stream>>>(cur, osb, hcur, cw, cb, hnext, featb, layer);
    { float* t_ = hcur; hcur = hnext; hnext = t_; }
  }
  k_head<<<(NB*NN*NT+255)/256, 256, 0, stream>>>(hcur, q1w, q1b, q2w, q2b, (float*)d_out);
}

// Round 12
// 2715.073 us; speedup vs baseline: 1.1353x; 1.1353x over previous
//
#include <hip/hip_runtime.h>

#define NB 8
#define NN 1024
#define NC 32
#define NT 20
#define NTI 10
#define NM 32     // iteration block size (16 wanted + 16 guard)
#define NK 16     // K_SPACE
#define NMT 4     // M_TIME
#define WE 64     // ELL width (max entries per row)
#define NQ 128
#define GNN (NB*NN)
#define RSL 24    // edge slots held in registers in k_cheb
#define PTC 16    // tc per block in k_project
#define PSEG 16   // n-segments in k_project

__device__ __forceinline__ float gelu_f(float x){
  return 0.5f * x * (1.0f + erff(x * 0.70710678118654752f));
}
__device__ __forceinline__ unsigned wanghash(unsigned s){
  s = (s ^ 61u) ^ (s >> 16); s *= 9u; s ^= s >> 4; s *= 0x27d4eb2du; s ^= s >> 15;
  return s;
}

// ---------------- initial lift; also writes channel-major feat[b][c][n] ------
__global__ void k_build_h0(const float* __restrict__ x, const float* __restrict__ pos,
                           const float* __restrict__ Wp, const float* __restrict__ bp,
                           float* __restrict__ h, float* __restrict__ feat){
  int idx = blockIdx.x*256 + threadIdx.x;
  if (idx >= NB*NN*NT*NC) return;
  int c = idx & (NC-1);
  int t = (idx/NC) % NT;
  int n = (idx/(NC*NT)) & (NN-1);
  int b = idx/(NC*NT*NN);
  const float* xr = x + (b*NN + n)*NTI;
  float acc = bp[c];
  #pragma unroll
  for (int i=0;i<NTI;i++) acc += xr[i]*Wp[i*NC+c];
  acc += pos[(b*NN+n)*2+0]*Wp[10*NC+c];
  acc += pos[(b*NN+n)*2+1]*Wp[11*NC+c];
  float tv = (float)(10+t) * (1.0f/29.0f);
  acc += tv*Wp[12*NC+c];
  h[idx] = acc;
  if (t == 0) feat[(((size_t)b*NC + c)<<10) + n] = acc;
}

// ---------------- all-pairs distances, GEMM-style 64x64 tiles ----------------
__global__ __launch_bounds__(256) void k_dist(const float* __restrict__ feat,
                          float* __restrict__ D){
  __shared__ float frow[NC][64];
  __shared__ float fcol[NC][64];
  int b = blockIdx.x & 7;
  int t = blockIdx.x >> 3;       // 0..255
  int r0 = (t >> 4) * 64;
  int m0 = (t & 15) * 64;
  const float* fb = feat + (((size_t)b*NC)<<10);
  #pragma unroll
  for (int it=0; it<8; it++){
    int idx = it*256 + threadIdx.x;
    int c = idx >> 6, j = idx & 63;
    frow[c][j] = fb[((size_t)c<<10) + r0 + j];
    fcol[c][j] = fb[((size_t)c<<10) + m0 + j];
  }
  __syncthreads();
  int rq = (threadIdx.x >> 4) << 2;
  int mq = (threadIdx.x & 15) << 2;
  float acc[4][4];
  #pragma unroll
  for (int i=0;i<4;i++)
    #pragma unroll
    for (int j=0;j<4;j++) acc[i][j] = 0.f;
  #pragma unroll 8
  for (int c=0;c<NC;c++){
    float rv[4], cv[4];
    #pragma unroll
    for (int i=0;i<4;i++) rv[i] = frow[c][rq+i];
    #pragma unroll
    for (int j=0;j<4;j++) cv[j] = fcol[c][mq+j];
    #pragma unroll
    for (int i=0;i<4;i++)
      #pragma unroll
      for (int j=0;j<4;j++){ float df = rv[i]-cv[j]; acc[i][j] += df*df; }
  }
  #pragma unroll
  for (int i=0;i<4;i++){
    float4 o;
    o.x = sqrtf(acc[i][0]); o.y = sqrtf(acc[i][1]);
    o.z = sqrtf(acc[i][2]); o.w = sqrtf(acc[i][3]);
    *(float4*)&D[(((size_t)(b<<10) + r0 + rq + i)<<10) + m0 + mq] = o;
  }
}

// ---------------- top-8 kNN + sigma from precomputed D -----------------------
__global__ __launch_bounds__(256) void k_knn(const float* __restrict__ D,
                           float* __restrict__ knnd, int* __restrict__ knni,
                           double* __restrict__ sig, int* __restrict__ cnt){
  int wave = threadIdx.x >> 6;
  int lane = threadIdx.x & 63;
  int b  = blockIdx.x & 7;
  int rg = blockIdx.x >> 3;
  int row = (b<<10) + rg*4 + wave;
  const float* Dr = D + ((size_t)row << 10);
  float d8[8]; int i8[8];
  #pragma unroll
  for (int j=0;j<8;j++){ d8[j]=1e30f; i8[j]=0x3fffffff; }
  double ssum = 0.0;
  for (int tile=0; tile<8; tile++){
    int m = tile*128 + lane;
    float da = Dr[m];
    float db = Dr[m+64];
    ssum += (double)da;
    if (da < d8[7] || (da == d8[7] && m < i8[7])){
      d8[7] = da; i8[7] = m;
      #pragma unroll
      for (int j=6;j>=0;j--){
        bool sw = (d8[j+1] < d8[j]) || (d8[j+1]==d8[j] && i8[j+1]<i8[j]);
        if (sw){ float td=d8[j]; d8[j]=d8[j+1]; d8[j+1]=td;
                 int ti=i8[j]; i8[j]=i8[j+1]; i8[j+1]=ti; }
      }
    }
    int m2 = m + 64;
    ssum += (double)db;
    if (db < d8[7] || (db == d8[7] && m2 < i8[7])){
      d8[7] = db; i8[7] = m2;
      #pragma unroll
      for (int j=6;j>=0;j--){
        bool sw = (d8[j+1] < d8[j]) || (d8[j+1]==d8[j] && i8[j+1]<i8[j]);
        if (sw){ float td=d8[j]; d8[j]=d8[j+1]; d8[j+1]=td;
                 int ti=i8[j]; i8[j]=i8[j+1]; i8[j+1]=ti; }
      }
    }
  }
  #pragma unroll
  for (int off=32; off>0; off>>=1) ssum += __shfl_down(ssum, off);
  if (lane==0){ atomicAdd(&sig[b], ssum); cnt[row] = 8; }
  int ptr = 0;
  for (int sel=0; sel<8; sel++){
    float dv = 1e30f; int iv = 0x3fffffff;
    #pragma unroll
    for (int j=0;j<8;j++) if (j==ptr){ dv=d8[j]; iv=i8[j]; }
    float bd = dv; int bi = iv;
    #pragma unroll
    for (int off=32; off>0; off>>=1){
      float od = __shfl_xor(bd, off);
      int oi = __shfl_xor(bi, off);
      if (od < bd || (od == bd && oi < bi)){ bd = od; bi = oi; }
    }
    if (dv == bd && iv == bi) ptr++;
    if (lane == sel){ knnd[row*8+sel] = bd; knni[row*8+sel] = bi; }
  }
}

// ---------------- fused dist+knn fallback (if ws too small) ------------------
__global__ __launch_bounds__(256) void k_dist_knn(const float* __restrict__ h,
                           const float* __restrict__ feat,
                           float* __restrict__ knnd, int* __restrict__ knni,
                           double* __restrict__ sig, int* __restrict__ cnt){
  __shared__ float fr_s[4][NC];
  int wave = threadIdx.x >> 6;
  int lane = threadIdx.x & 63;
  int b  = blockIdx.x & 7;
  int rg = blockIdx.x >> 3;
  int row = (b<<10) + rg*4 + wave;
  if (threadIdx.x < 4*NC){
    int w = threadIdx.x >> 5, c = threadIdx.x & 31;
    int rr = (b<<10) + rg*4 + w;
    fr_s[w][c] = h[((size_t)rr*NT)*NC + c];
  }
  __syncthreads();
  float d8[8]; int i8[8];
  #pragma unroll
  for (int j=0;j<8;j++){ d8[j]=1e30f; i8[j]=0x3fffffff; }
  double ssum = 0.0;
  const float* fc_b = feat + (((size_t)b*NC)<<10);
  for (int tile=0; tile<8; tile++){
    int m = tile*128 + lane;
    float d2a = 0.f, d2b = 0.f;
    #pragma unroll 8
    for (int c=0;c<NC;c++){
      float fc = fr_s[wave][c];
      const float* fp = fc_b + ((size_t)c<<10) + m;
      float dfa = fc - fp[0];
      float dfb = fc - fp[64];
      d2a += dfa*dfa; d2b += dfb*dfb;
    }
    float da = sqrtf(d2a);
    ssum += (double)da;
    if (da < d8[7] || (da == d8[7] && m < i8[7])){
      d8[7] = da; i8[7] = m;
      #pragma unroll
      for (int j=6;j>=0;j--){
        bool sw = (d8[j+1] < d8[j]) || (d8[j+1]==d8[j] && i8[j+1]<i8[j]);
        if (sw){ float td=d8[j]; d8[j]=d8[j+1]; d8[j+1]=td;
                 int ti=i8[j]; i8[j]=i8[j+1]; i8[j+1]=ti; }
      }
    }
    int m2 = m + 64;
    float db = sqrtf(d2b);
    ssum += (double)db;
    if (db < d8[7] || (db == d8[7] && m2 < i8[7])){
      d8[7] = db; i8[7] = m2;
      #pragma unroll
      for (int j=6;j>=0;j--){
        bool sw = (d8[j+1] < d8[j]) || (d8[j+1]==d8[j] && i8[j+1]<i8[j]);
        if (sw){ float td=d8[j]; d8[j]=d8[j+1]; d8[j+1]=td;
                 int ti=i8[j]; i8[j]=i8[j+1]; i8[j+1]=ti; }
      }
    }
  }
  #pragma unroll
  for (int off=32; off>0; off>>=1) ssum += __shfl_down(ssum, off);
  if (lane==0){ atomicAdd(&sig[b], ssum); cnt[row] = 8; }
  int ptr = 0;
  for (int sel=0; sel<8; sel++){
    float dv = 1e30f; int iv = 0x3fffffff;
    #pragma unroll
    for (int j=0;j<8;j++) if (j==ptr){ dv=d8[j]; iv=i8[j]; }
    float bd = dv; int bi = iv;
    #pragma unroll
    for (int off=32; off>0; off>>=1){
      float od = __shfl_xor(bd, off);
      int oi = __shfl_xor(bi, off);
      if (od < bd || (od == bd && oi < bi)){ bd = od; bi = oi; }
    }
    if (dv == bd && iv == bi) ptr++;
    if (lane == sel){ knnd[row*8+sel] = bd; knni[row*8+sel] = bi; }
  }
}

// ---------------- symmetrized sparse A in transposed ELL form ----------------
__global__ void k_build_ell(const float* __restrict__ knnd, const int* __restrict__ knni,
                            const double* __restrict__ sig, int* __restrict__ cnt,
                            unsigned short* __restrict__ ecolT, float* __restrict__ evalT){
  int row = blockIdx.x*256 + threadIdx.x;
  if (row >= NB*NN) return;
  int b = row >> 10;
  float sigma = (float)(sig[b] * (1.0/((double)NN*(double)NN)));
  float s2 = sigma*sigma;
  int rloc = row & (NN-1);
  #pragma unroll
  for (int j=0;j<8;j++){
    float d = knnd[row*8+j];
    int m = knni[row*8+j];
    float v = 0.5f * expf(-d/s2);
    ecolT[(size_t)j*GNN + row] = (unsigned short)m;
    evalT[(size_t)j*GNN + row] = v;
    int grow = (b<<10) + m;
    int p = atomicAdd(&cnt[grow], 1);
    if (p < WE){ ecolT[(size_t)p*GNN + grow] = (unsigned short)rloc;
                 evalT[(size_t)p*GNN + grow] = v; }
  }
}

__global__ void k_degnorm(const int* __restrict__ cnt, const float* __restrict__ evalT,
                          float* __restrict__ deg, float* __restrict__ dinv){
  int row = blockIdx.x*256 + threadIdx.x;
  if (row >= NB*NN) return;
  int c = cnt[row]; if (c > WE) c = WE;
  float s = 0.f;
  for (int j=0;j<c;j++) s += evalT[(size_t)j*GNN + row];
  deg[row] = s;
  dinv[row] = 1.0f/sqrtf(s + 1e-6f);
}

__global__ void k_normell(const int* __restrict__ cnt, const unsigned short* __restrict__ ecolT,
                          float* __restrict__ evalT, const float* __restrict__ deg,
                          const float* __restrict__ dinv, float* __restrict__ dval){
  int row = blockIdx.x*256 + threadIdx.x;
  if (row >= NB*NN) return;
  int b = row >> 10;
  const float* dv = dinv + (b<<10);
  float di = dinv[row];
  int c = cnt[row]; if (c > WE) c = WE;
  for (int j=0;j<c;j++){
    int col = ecolT[(size_t)j*GNN + row];
    evalT[(size_t)j*GNN + row] = evalT[(size_t)j*GNN + row] * (di * dv[col]);
  }
  dval[row] = di*di*deg[row];
}

// ---------------- eigensolver: init block -----------------------------------
__global__ void k_initX(const float* __restrict__ deg, float* __restrict__ X, float* __restrict__ aint){
  int idx = blockIdx.x*256+threadIdx.x;
  if (idx >= NB*NM*NN) return;
  int n = idx & (NN-1);
  int j = (idx >> 10) & (NM-1);
  int b = idx >> 15;
  float v;
  if (j == 0) v = sqrtf(deg[(b<<10)+n] + 1e-6f);   // exact 0-eigenvector of Lhat
  else {
    unsigned hsh = wanghash((unsigned)idx * 2654435761u + 12345u);
    v = ((hsh >> 8) * (1.0f/16777216.0f)) - 0.5f;
  }
  X[idx] = v;
  if (n == 0 && j == 1) aint[b] = 1.0f;
}

// ---------------- Chebyshev filter: 1024 thr, 1 row/thread -------------------
// FP order per row identical to the 512x2 version (rows are independent).
__global__ __launch_bounds__(1024) void k_cheb(const int* __restrict__ cnt,
                        const unsigned short* __restrict__ ecolT,
                        const float* __restrict__ evalT, const float* __restrict__ dval,
                        float* __restrict__ X, const float* __restrict__ aint, int ndeg){
  __shared__ float bufA[NN];
  __shared__ float bufB[NN];
  int b = blockIdx.x & 7;
  int col = blockIdx.x >> 3;
  float a = aint[b];
  const float bhi = 2.0005f;
  float e  = 0.5f*(bhi - a);
  float cc = 0.5f*(bhi + a);
  float inv_e = 1.0f/e;
  const int rowbase = b << 10;
  float* Xc = X + ((size_t)b*NM + col)*NN;
  int r0 = threadIdx.x;
  bufA[r0] = Xc[r0];
  int c0 = cnt[rowbase+r0]; if (c0 > WE) c0 = WE;
  float dv0 = dval[rowbase+r0];
  float ev0[RSL];
  int   ic0[RSL];
  #pragma unroll
  for (int j=0;j<RSL;j++){
    ic0[j] = (j<c0)? (int)ecolT[(size_t)j*GNN + rowbase + r0] : 0;
    ev0[j] = (j<c0)? evalT[(size_t)j*GNN + rowbase + r0] : 0.f;
  }
  int e0 = c0 - RSL; if (e0 < 0) e0 = 0;
  const unsigned short* pe0 = ecolT + (size_t)RSL*GNN + rowbase + r0;
  const float* pv0 = evalT + (size_t)RSL*GNN + rowbase + r0;
  __syncthreads();
  float* cur = bufA; float* prv = bufB;
  for (int k=0;k<ndeg;k++){
    float f = (k==0)? inv_e : 2.0f*inv_e;
    float x0 = cur[r0];
    float acc0 = dv0*x0;
    #pragma unroll
    for (int j=0;j<RSL;j++)
      acc0 -= ev0[j]*cur[ic0[j]];
    for (int j=0;j<e0;j++)   // rare overflow rows
      acc0 -= pv0[(size_t)j*GNN] * cur[pe0[(size_t)j*GNN]];
    float n0 = f*(acc0 - cc*x0);
    if (k > 0) n0 -= prv[r0];
    prv[r0] = n0;
    float* t_ = cur; cur = prv; prv = t_;
    __syncthreads();
  }
  Xc[r0] = cur[r0];
}

// ---------------- G = A^T B (f64 accumulate), one row of G per wg ------------
__global__ void k_gram(const float* __restrict__ A, const float* __restrict__ Bm,
                       double* __restrict__ G){
  __shared__ float ai[NN];
  __shared__ double pd[NM][8];
  int b = blockIdx.x & 7, i = blockIdx.x >> 3;
  const float* Ac = A + ((size_t)b*NM + i)*NN;
  for (int n=threadIdx.x; n<NN; n+=256) ai[n] = Ac[n];
  __syncthreads();
  int j = threadIdx.x & 31, seg = threadIdx.x >> 5;
  const float* Bc = Bm + ((size_t)b*NM + j)*NN + seg*128;
  const float* as = ai + seg*128;
  double s = 0.0;
  for (int n=0;n<128;n++) s += (double)as[n]*(double)Bc[n];
  pd[j][seg] = s;
  __syncthreads();
  if (threadIdx.x < NM){
    double t = 0.0;
    #pragma unroll
    for (int q=0;q<8;q++) t += pd[threadIdx.x][q];
    G[((size_t)b*NM + i)*NM + threadIdx.x] = t;
  }
}

// ---------------- chol(G)->R^{-1}->apply, 1-wave blocks, 64 nodes/block ------
__global__ __launch_bounds__(64) void k_cholapply(const double* __restrict__ G,
                        const float* __restrict__ Xin, float* __restrict__ Xout,
                        float* __restrict__ aint, int reset){
  __shared__ double L[NM][NM];
  __shared__ double Ri[NM][NM];
  int b = blockIdx.x >> 4;
  int seg = blockIdx.x & 15;
  int tid = threadIdx.x;
  for (int idx=tid; idx<NM*NM; idx+=64) L[idx>>5][idx&31] = G[(size_t)b*NM*NM + idx];
  __syncthreads();
  for (int k=0;k<NM;k++){
    if (tid == 0){
      double orig = L[k][k];
      double s = orig;
      for (int p=0;p<k;p++) s -= L[k][p]*L[k][p];
      double floorv = orig*1e-15; if (floorv < 1e-30) floorv = 1e-30;
      if (s < floorv) s = floorv;
      L[k][k] = sqrt(s);
    }
    __syncthreads();
    if (tid > k && tid < NM){
      double s = L[tid][k];
      for (int p=0;p<k;p++) s -= L[tid][p]*L[k][p];
      L[tid][k] = s / L[k][k];
    }
    __syncthreads();
  }
  if (tid < NM){
    int j = tid;
    Ri[j][j] = 1.0 / L[j][j];
    for (int i=j-1;i>=0;i--){
      double s = 0.0;
      for (int k2=i+1;k2<=j;k2++) s += L[k2][i]*Ri[k2][j];
      Ri[i][j] = -s / L[i][i];
    }
  }
  __syncthreads();
  int n = seg*64 + tid;
  float xv[NM];
  #pragma unroll
  for (int j=0;j<NM;j++) xv[j] = Xin[((size_t)b*NM + j)*NN + n];
  for (int jn=0;jn<NM;jn++){
    double acc = 0.0;
    for (int j=0;j<=jn;j++) acc += (double)xv[j] * Ri[j][jn];
    Xout[((size_t)b*NM + jn)*NN + n] = (float)acc;
  }
  if (reset && seg==0 && tid==0) aint[b] = 0.02f;
}

// ---------------- fused spmv + Gram row + Gershgorin interval bound ----------
// 512 threads: SpMV strided by 512 (per-row FP identical); Gram phase keeps the
// exact tid<256 partition of the 256-thread version (FP identical).
__global__ __launch_bounds__(512) void k_spmv_gersh(const int* __restrict__ cnt,
                        const unsigned short* __restrict__ ecolT,
                        const float* __restrict__ evalT, const float* __restrict__ dval,
                        const float* __restrict__ X, float* __restrict__ aint){
  __shared__ float xc[NN];
  __shared__ float yc[NN];
  __shared__ double pd[NM][8];
  int b = blockIdx.x & 7, j = blockIdx.x >> 3;
  const float* Xc = X + ((size_t)b*NM + j)*NN;
  for (int n=threadIdx.x; n<NN; n+=512) xc[n] = Xc[n];
  __syncthreads();
  int rowbase = b << 10;
  for (int r=threadIdx.x; r<NN; r+=512){
    int c = cnt[rowbase+r]; if (c > WE) c = WE;
    float acc = dval[rowbase+r]*xc[r];
    const unsigned short* pe = ecolT + rowbase + r;
    const float* pv = evalT + rowbase + r;
    for (int jj=0;jj<c;jj++){
      acc -= pv[0]*xc[pe[0]];
      pe += GNN; pv += GNN;
    }
    yc[r] = acc;
  }
  __syncthreads();
  if (threadIdx.x < 256){
    int i = threadIdx.x >> 3, seg = threadIdx.x & 7;
    const float* Xi = X + ((size_t)b*NM + i)*NN + seg*128;
    const float* ys = yc + seg*128;
    double s = 0.0;
    for (int k=0;k<128;k++) s += (double)Xi[k]*(double)ys[k];
    pd[i][seg] = s;
  }
  __syncthreads();
  if (threadIdx.x < NM){
    double g = 0.0;
    #pragma unroll
    for (int q=0;q<8;q++) g += pd[threadIdx.x][q];
    double contrib = (threadIdx.x==j)? g : fabs(g);
    #pragma unroll
    for (int off=16; off>0; off>>=1) contrib += __shfl_down(contrib, off, 32);
    if (threadIdx.x == 0){
      float av = (float)contrib*1.02f + 1e-4f;
      av = fminf(fmaxf(av, 0.02f), 1.5f);
      atomicMax((unsigned int*)&aint[b], __float_as_uint(av));
    }
  }
}

// ---------------- fused spmv + Gram row write (final RR), 512 thr ------------
__global__ __launch_bounds__(512) void k_spmv_gram(const int* __restrict__ cnt,
                        const unsigned short* __restrict__ ecolT,
                        const float* __restrict__ evalT, const float* __restrict__ dval,
                        const float* __restrict__ X, double* __restrict__ G){
  __shared__ float xc[NN];
  __shared__ float yc[NN];
  __shared__ double pd[NM][8];
  int b = blockIdx.x & 7, j = blockIdx.x >> 3;
  const float* Xc = X + ((size_t)b*NM + j)*NN;
  for (int n=threadIdx.x; n<NN; n+=512) xc[n] = Xc[n];
  __syncthreads();
  int rowbase = b << 10;
  for (int r=threadIdx.x; r<NN; r+=512){
    int c = cnt[rowbase+r]; if (c > WE) c = WE;
    float acc = dval[rowbase+r]*xc[r];
    const unsigned short* pe = ecolT + rowbase + r;
    const float* pv = evalT + rowbase + r;
    for (int jj=0;jj<c;jj++){
      acc -= pv[0]*xc[pe[0]];
      pe += GNN; pv += GNN;
    }
    yc[r] = acc;
  }
  __syncthreads();
  if (threadIdx.x < 256){
    int i = threadIdx.x >> 3, seg = threadIdx.x & 7;
    const float* Xi = X + ((size_t)b*NM + i)*NN + seg*128;
    const float* ys = yc + seg*128;
    double s = 0.0;
    for (int k=0;k<128;k++) s += (double)Xi[k]*(double)ys[k];
    pd[i][seg] = s;
  }
  __syncthreads();
  if (threadIdx.x < NM){
    double g = 0.0;
    #pragma unroll
    for (int q=0;q<8;q++) g += pd[threadIdx.x][q];
    G[((size_t)b*NM + j)*NM + threadIdx.x] = g;   // G[j][i]; jacobi symmetrizes
  }
}

// ---------------- 32x32 Jacobi (1-wave block), Vp out (f32) ------------------
__global__ __launch_bounds__(64) void k_jacobi(const double* __restrict__ Gd,
                        float* __restrict__ Vpf, int sweeps){
  __shared__ float S[NM][NM];
  __shared__ float V[NM][NM];
  __shared__ float cs_[16], sn_[16];
  __shared__ int pp_[16], qq_[16];
  __shared__ int perm[NM];
  int b = blockIdx.x, l = threadIdx.x;
  for (int idx=l; idx<NM*NM; idx+=64){
    int i = idx>>5, j = idx&31;
    S[i][j] = (float)(0.5*(Gd[(size_t)b*NM*NM + i*NM + j] + Gd[(size_t)b*NM*NM + j*NM + i]));
    V[i][j] = (i==j)? 1.0f : 0.0f;
  }
  __syncthreads();
  for (int sw=0; sw<sweeps; sw++){
    for (int r=0; r<31; r++){
      if (l < 16){
        int p, q;
        if (l == 0){ p = r; q = 31; }
        else { p = (r + l) % 31; q = (r + 31 - l) % 31; }
        if (p > q){ int t_=p; p=q; q=t_; }
        float apq = S[p][q];
        float c = 1.0f, s = 0.0f;
        if (fabsf(apq) > 1e-30f){
          float tau = (S[q][q] - S[p][p]) / (2.0f*apq);
          float tt = (tau >= 0.f ? 1.0f : -1.0f) / (fabsf(tau) + sqrtf(1.0f + tau*tau));
          c = 1.0f/sqrtf(1.0f + tt*tt); s = tt*c;
        }
        cs_[l]=c; sn_[l]=s; pp_[l]=p; qq_[l]=q;
      }
      __syncthreads();
      for (int tsk=l; tsk<512; tsk+=64){
        int i = tsk >> 4, kk = tsk & 15;
        int p = pp_[kk], q = qq_[kk];
        float c = cs_[kk], s = sn_[kk];
        float sp = S[i][p], sq = S[i][q];
        S[i][p] = c*sp - s*sq; S[i][q] = s*sp + c*sq;
        float vp = V[i][p], vq = V[i][q];
        V[i][p] = c*vp - s*vq; V[i][q] = s*vp + c*vq;
      }
      __syncthreads();
      for (int tsk=l; tsk<512; tsk+=64){
        int jc = tsk >> 4, kk = tsk & 15;
        int p = pp_[kk], q = qq_[kk];
        float c = cs_[kk], s = sn_[kk];
        float sp = S[p][jc], sq = S[q][jc];
        S[p][jc] = c*sp - s*sq; S[q][jc] = s*sp + c*sq;
      }
      __syncthreads();
    }
  }
  // parallel rank sort of diag(S) ascending (tie-break by index)
  if (l < NM){
    float v = S[l][l];
    int rank = 0;
    #pragma unroll
    for (int i=0;i<NM;i++){
      float vi = S[i][i];
      rank += (vi < v || (vi == v && i < l)) ? 1 : 0;
    }
    perm[rank] = l;
  }
  __syncthreads();
  for (int idx=l; idx<NM*NM; idx+=64){
    int i = idx>>5, j = idx&31;
    Vpf[(size_t)b*NM*NM + i*NM + j] = V[i][perm[j]];
  }
}

// ---------------- Xout = Xin * Vp (f32), quarter of nodes per block ----------
__global__ __launch_bounds__(256) void k_applyVf(const float* __restrict__ Xin,
                        const float* __restrict__ Vpf, float* __restrict__ Xout){
  __shared__ float Ms[NM*NM];
  int b = blockIdx.x >> 2;
  int n = (blockIdx.x & 3)*256 + threadIdx.x;
  for (int idx=threadIdx.x; idx<NM*NM; idx+=256) Ms[idx] = Vpf[(size_t)b*NM*NM + idx];
  __syncthreads();
  float xv[NM];
  #pragma unroll
  for (int j=0;j<NM;j++) xv[j] = Xin[((size_t)b*NM + j)*NN + n];
  #pragma unroll
  for (int jn=0;jn<NM;jn++){
    float acc = 0.f;
    #pragma unroll
    for (int j=0;j<NM;j++) acc += xv[j]*Ms[j*NM + jn];
    Xout[((size_t)b*NM + jn)*NN + n] = acc;
  }
}

// ---------------- xs[b][k][tc] = sum_n X[b][k][n] * h[b][n][tc] --------------
__global__ __launch_bounds__(256) void k_project(const float* __restrict__ X, const float* __restrict__ h,
                          float* __restrict__ xs){
  __shared__ float Xs[NK][NN];             // 64KB
  __shared__ float red[PSEG][NK][PTC+1];   // ~17KB
  int b = blockIdx.x & 7;
  int chunk = blockIdx.x >> 3;             // 0..39
  int tc0 = chunk * PTC;
  for (int idx=threadIdx.x; idx<NK*NN; idx+=256){
    int k = idx >> 10, n = idx & (NN-1);
    Xs[k][n] = X[((size_t)b*NM + k)*NN + n];
  }
  __syncthreads();
  int tcl = threadIdx.x & (PTC-1);
  int seg = threadIdx.x >> 4;              // 0..15
  const float* hb = h + (size_t)b*NN*NT*NC + tc0 + tcl;
  float acc[NK];
  #pragma unroll
  for (int k=0;k<NK;k++) acc[k]=0.f;
  int n0 = seg*(NN/PSEG);
  for (int n=n0; n<n0+(NN/PSEG); n++){
    float v = hb[(size_t)n*NT*NC];
    #pragma unroll
    for (int k=0;k<NK;k++) acc[k] += Xs[k][n]*v;
  }
  #pragma unroll
  for (int k=0;k<NK;k++) red[seg][k][tcl] = acc[k];
  __syncthreads();
  int k = threadIdx.x >> 4;
  int t2 = threadIdx.x & (PTC-1);
  float s = 0.f;
  #pragma unroll
  for (int q=0;q<PSEG;q++) s += red[q][k][t2];
  xs[((size_t)b*NK + k)*NT*NC + tc0 + t2] = s;
}

// ---------------- rfft(:4) -> complex channel mix -> irfft -------------------
__global__ __launch_bounds__(64) void k_timefilter(const float* __restrict__ xs, const float* __restrict__ fwr,
                             const float* __restrict__ fwi, float* __restrict__ osb, int layer){
  __shared__ float xst[NT*NC];
  __shared__ float xfr[NC][NMT];
  __shared__ float xfi[NC][NMT];
  int b = blockIdx.x >> 4, k = blockIdx.x & 15;
  const float* xin = xs + ((size_t)b*NK + k)*NT*NC;
  for (int idx=threadIdx.x; idx<NT*NC; idx+=64) xst[idx] = xin[idx];
  __syncthreads();
  int l = threadIdx.x;
  if (l < NC){
    float ar0=0,ar1=0,ar2=0,ar3=0, ai1=0,ai2=0,ai3=0;
    for (int t=0;t<NT;t++){
      float v = xst[t*NC + l];
      float w1 = 0.31415926535897932f * (float)t;  // 2*pi*t/20
      ar0 += v;
      ar1 += v*cosf(w1);       ai1 -= v*sinf(w1);
      ar2 += v*cosf(2.f*w1);   ai2 -= v*sinf(2.f*w1);
      ar3 += v*cosf(3.f*w1);   ai3 -= v*sinf(3.f*w1);
    }
    xfr[l][0]=ar0; xfi[l][0]=0.f;
    xfr[l][1]=ar1; xfi[l][1]=ai1;
    xfr[l][2]=ar2; xfi[l][2]=ai2;
    xfr[l][3]=ar3; xfi[l][3]=ai3;
  }
  __syncthreads();
  if (l < NC){
    int o = l;
    float ofr[NMT], ofi[NMT];
    #pragma unroll
    for (int f=0; f<NMT; f++){ ofr[f]=0.f; ofi[f]=0.f; }
    for (int i=0;i<NC;i++){
      size_t wbase = ((((size_t)layer*NC + i)*NC + o)*NK + k)*NMT;
      #pragma unroll
      for (int f=0; f<NMT; f++){
        float wr = fwr[wbase+f], wi2 = fwi[wbase+f];
        float xr = xfr[i][f], xi = xfi[i][f];
        ofr[f] += xr*wr - xi*wi2;
        ofi[f] += xr*wi2 + xi*wr;
      }
    }
    float* outp = osb + ((size_t)b*NK + k)*NT*NC;
    for (int t=0;t<NT;t++){
      float w1 = 0.31415926535897932f * (float)t;
      float acc = ofr[0];
      acc += 2.f*(ofr[1]*cosf(w1)     - ofi[1]*sinf(w1));
      acc += 2.f*(ofr[2]*cosf(2.f*w1) - ofi[2]*sinf(2.f*w1));
      acc += 2.f*(ofr[3]*cosf(3.f*w1) - ofi[3]*sinf(3.f*w1));
      outp[t*NC + o] = acc * 0.05f;
    }
  }
}

// ---------------- h' = basis*os + cw*h + cb, gelu; also writes feat ----------
__global__ __launch_bounds__(256) void k_update(const float* __restrict__ X, const float* __restrict__ osb,
                         const float* __restrict__ h, const float* __restrict__ cw,
                         const float* __restrict__ cb, float* __restrict__ hout,
                         float* __restrict__ feat, int layer){
  __shared__ float os_s[NK*NT*NC];   // 40KB
  __shared__ float cwT[NC*NC];
  __shared__ float Xl[NK][32];
  __shared__ float cbs[NC];
  int b = blockIdx.x & 7;
  int n0 = (blockIdx.x >> 3)*32;
  for (int idx=threadIdx.x; idx<NK*NT*NC; idx+=256) os_s[idx] = osb[(size_t)b*NK*NT*NC + idx];
  for (int idx=threadIdx.x; idx<NC*NC; idx+=256){
    int o = idx/NC, i = idx%NC;
    cwT[i*NC + o] = cw[((size_t)layer*NC + o)*NC + i];
  }
  if (threadIdx.x < NC) cbs[threadIdx.x] = cb[layer*NC + threadIdx.x];
  for (int idx=threadIdx.x; idx<NK*32; idx+=256){
    int k = idx >> 5, nl = idx & 31;
    Xl[k][nl] = X[((size_t)b*NM + k)*NN + n0 + nl];
  }
  __syncthreads();
  for (int tsk=threadIdx.x; tsk<32*NT; tsk+=256){
    int t = tsk % NT, nl = tsk / NT;
    int n = n0 + nl;
    const float* hr = h + (((size_t)b*NN + n)*NT + t)*NC;
    float acc[NC];
    #pragma unroll
    for (int o=0;o<NC;o++) acc[o] = cbs[o];
    #pragma unroll
    for (int k=0;k<NK;k++){
      float xv = Xl[k][nl];
      const float* osr = os_s + (k*NT + t)*NC;
      #pragma unroll
      for (int o=0;o<NC;o++) acc[o] += xv*osr[o];
    }
    for (int i=0;i<NC;i++){
      float hv = hr[i];
      const float* cwr = cwT + i*NC;
      #pragma unroll
      for (int o=0;o<NC;o++) acc[o] += hv*cwr[o];
    }
    float* outp = hout + (((size_t)b*NN + n)*NT + t)*NC;
    if (layer < 3){
      #pragma unroll
      for (int o=0;o<NC;o++){
        float v = gelu_f(acc[o]);
        outp[o] = v;
        if (t == 0) feat[(((size_t)b*NC + o)<<10) + n] = v;
      }
    } else {
      #pragma unroll
      for (int o=0;o<NC;o++){
        outp[o] = acc[o];
        if (t == 0) feat[(((size_t)b*NC + o)<<10) + n] = acc[o];
      }
    }
  }
}

// ---------------- head: gelu(h@q1w+q1b)@q2w + q2b ----------------------------
__global__ __launch_bounds__(256) void k_head(const float* __restrict__ h, const float* __restrict__ q1w,
                       const float* __restrict__ q1b, const float* __restrict__ q2w,
                       const float* __restrict__ q2b, float* __restrict__ out){
  __shared__ float w1[NC*NQ];
  __shared__ float b1[NQ], w2[NQ];
  for (int idx=threadIdx.x; idx<NC*NQ; idx+=256) w1[idx] = q1w[idx];
  if (threadIdx.x < NQ){ b1[threadIdx.x] = q1b[threadIdx.x]; w2[threadIdx.x] = q2w[threadIdx.x]; }
  __syncthreads();
  int idx = blockIdx.x*256 + threadIdx.x;
  if (idx >= NB*NN*NT) return;
  const float* hr = h + (size_t)idx*NC;
  float hv[NC];
  #pragma unroll
  for (int i=0;i<NC;i++) hv[i] = hr[i];
  float res = q2b[0];
  for (int j=0;j<NQ;j++){
    float z = b1[j];
    #pragma unroll
    for (int i=0;i<NC;i++) z += hv[i]*w1[i*NQ + j];
    res += gelu_f(z)*w2[j];
  }
  out[idx] = res;
}

// ============================================================================
extern "C" void kernel_launch(void* const* d_in, const int* in_sizes, int n_in,
                              void* d_out, int out_size, void* d_ws, size_t ws_size,
                              hipStream_t stream){
  (void)in_sizes; (void)n_in; (void)out_size;
  const float* x   = (const float*)d_in[0];
  const float* pos = (const float*)d_in[1];
  const float* Wp  = (const float*)d_in[2];
  const float* bp  = (const float*)d_in[3];
  const float* fwr = (const float*)d_in[4];
  const float* fwi = (const float*)d_in[5];
  const float* cw  = (const float*)d_in[6];
  const float* cb  = (const float*)d_in[7];
  const float* q1w = (const float*)d_in[8];
  const float* q1b = (const float*)d_in[9];
  const float* q2w = (const float*)d_in[10];
  const float* q2b = (const float*)d_in[11];

  char* p = (char*)d_ws;
  auto take = [&](size_t bytes)->void*{
    void* r = (void*)p;
    p += (bytes + 255) & ~(size_t)255;
    return r;
  };
  float*  hA    = (float*) take(sizeof(float)*NB*NN*NT*NC);
  float*  hB    = (float*) take(sizeof(float)*NB*NN*NT*NC);
  float*  featb = (float*) take(sizeof(float)*NB*NC*NN);
  float*  knnd  = (float*) take(sizeof(float)*NB*NN*8);
  int*    knni  = (int*)   take(sizeof(int)*NB*NN*8);
  double* sig   = (double*)take(sizeof(double)*NB);
  int*    cntb  = (int*)   take(sizeof(int)*NB*NN);
  unsigned short* ecolT = (unsigned short*) take(sizeof(unsigned short)*(size_t)GNN*WE);
  float*  evalT = (float*) take(sizeof(float)*(size_t)GNN*WE);
  float*  deg   = (float*) take(sizeof(float)*NB*NN);
  float*  dinv  = (float*) take(sizeof(float)*NB*NN);
  float*  dval  = (float*) take(sizeof(float)*NB*NN);
  float*  Xb    = (float*) take(sizeof(float)*NB*NM*NN);
  float*  Yb    = (float*) take(sizeof(float)*NB*NM*NN);
  double* Gd    = (double*)take(sizeof(double)*NB*NM*NM);
  float*  Vpf   = (float*) take(sizeof(float)*NB*NM*NM);
  float*  aint  = (float*) take(sizeof(float)*NB);
  float*  xs    = (float*) take(sizeof(float)*NB*NK*NT*NC);
  float*  osb   = (float*) take(sizeof(float)*NB*NK*NT*NC);
  if ((size_t)(p - (char*)d_ws) > ws_size) return;  // ws too small -> loud failure
  // optional 32MB distance matrix (split path); fall back to fused if no room
  float* Dbuf = nullptr;
  {
    size_t used = (size_t)(p - (char*)d_ws);
    size_t needD = ((sizeof(float)*(size_t)GNN*NN) + 255) & ~(size_t)255;
    if (used + needD <= ws_size) Dbuf = (float*)take(sizeof(float)*(size_t)GNN*NN);
  }

  k_build_h0<<<(NB*NN*NT*NC+255)/256, 256, 0, stream>>>(x, pos, Wp, bp, hA, featb);

  float* hcur = hA; float* hnext = hB;
  for (int layer=0; layer<4; layer++){
    hipMemsetAsync(sig, 0, sizeof(double)*NB, stream);
    if (Dbuf){
      k_dist<<<NB*256, 256, 0, stream>>>(featb, Dbuf);
      k_knn<<<NB*NN/4, 256, 0, stream>>>(Dbuf, knnd, knni, sig, cntb);
    } else {
      k_dist_knn<<<NB*NN/4, 256, 0, stream>>>(hcur, featb, knnd, knni, sig, cntb);
    }
    k_build_ell<<<NB*NN/256, 256, 0, stream>>>(knnd, knni, sig, cntb, ecolT, evalT);
    k_degnorm<<<NB*NN/256, 256, 0, stream>>>(cntb, evalT, deg, dinv);
    k_normell<<<NB*NN/256, 256, 0, stream>>>(cntb, ecolT, evalT, deg, dinv, dval);
    k_initX<<<NB*NM*NN/256, 256, 0, stream>>>(deg, Xb, aint);
    float* cur = Xb; float* oth = Yb;
    // round 0: deg 24 on [1.0, 2.0005], then QR + interval estimate
    k_cheb<<<NB*NM, 1024, 0, stream>>>(cntb, ecolT, evalT, dval, cur, aint, 24);
    k_gram<<<NB*NM, 256, 0, stream>>>(cur, cur, Gd);
    k_cholapply<<<NB*16, 64, 0, stream>>>(Gd, cur, oth, aint, 1);
    { float* t_ = cur; cur = oth; oth = t_; }
    k_spmv_gersh<<<NB*NM, 512, 0, stream>>>(cntb, ecolT, evalT, dval, cur, aint);
    // round 1: deg 32 on adapted interval, then QR
    k_cheb<<<NB*NM, 1024, 0, stream>>>(cntb, ecolT, evalT, dval, cur, aint, 32);
    k_gram<<<NB*NM, 256, 0, stream>>>(cur, cur, Gd);
    k_cholapply<<<NB*16, 64, 0, stream>>>(Gd, cur, oth, aint, 0);
    { float* t_ = cur; cur = oth; oth = t_; }
    // final Rayleigh-Ritz: G = X^T L X (fused), Jacobi (1 sweep), apply
    k_spmv_gram<<<NB*NM, 512, 0, stream>>>(cntb, ecolT, evalT, dval, cur, Gd);
    k_jacobi<<<NB, 64, 0, stream>>>(Gd, Vpf, 1);
    k_applyVf<<<NB*4, 256, 0, stream>>>(cur, Vpf, oth);
    { float* t_ = cur; cur = oth; oth = t_; }

    k_project<<<NB*40, 256, 0, stream>>>(cur, hcur, xs);
    k_timefilter<<<NB*NK, 64, 0, stream>>>(xs, fwr, fwi, osb, layer);
    k_update<<<NB*32, 256, 0, stream>>>(cur, osb, hcur, cw, cb, hnext, featb, layer);
    { float* t_ = hcur; hcur = hnext; hnext = t_; }
  }
  k_head<<<(NB*NN*NT+255)/256, 256, 0, stream>>>(hcur, q1w, q1b, q2w, q2b, (float*)d_out);
}